// Round 9
// baseline (5385.875 us; speedup 1.0000x reference)
//
#include <hip/hip_runtime.h>
#include <stdint.h>

#define D 1024

typedef unsigned long long u64;
typedef unsigned int u32;

// ---------- monotonic float<->uint mapping for atomic max ----------
__device__ __forceinline__ u32 enc_f(float f) {
    u32 b = __float_as_uint(f);
    return (b & 0x80000000u) ? ~b : (b | 0x80000000u);
}
__device__ __forceinline__ float dec_f(u32 u) {
    u32 b = (u & 0x80000000u) ? (u ^ 0x80000000u) : ~u;
    return __uint_as_float(b);
}

// ---------- kernel A: max(X), max|X| ----------
__global__ void k_maxred(const float* __restrict__ X, u32* scal) {
    float mx = -INFINITY, ma = 0.f;
    int stride = gridDim.x * blockDim.x;
    for (int i = blockIdx.x * blockDim.x + threadIdx.x; i < D * D; i += stride) {
        float v = X[i];
        mx = fmaxf(mx, v);
        ma = fmaxf(ma, fabsf(v));
    }
    for (int o = 32; o; o >>= 1) {
        mx = fmaxf(mx, __shfl_xor(mx, o));
        ma = fmaxf(ma, __shfl_xor(ma, o));
    }
    if ((threadIdx.x & 63) == 0) {
        atomicMax(&scal[0], enc_f(mx));  // max_sim
        atomicMax(&scal[1], enc_f(ma));  // max|X|
    }
}

// ---------- kernel B: init dist (f32) and cross (f32) matrices ----------
__global__ void k_init(const float* __restrict__ X, const float* __restrict__ W,
                       float* __restrict__ dist, float* __restrict__ cross,
                       const u32* __restrict__ scal) {
    int idx = blockIdx.x * blockDim.x + threadIdx.x;
    if (idx >= D * D) return;
    float max_sim = dec_f(scal[0]);
    float MAXD = __fmul_rn(dec_f(scal[1]), 1000.0f);
    int i = idx >> 10, j = idx & (D - 1);
    float x = X[idx];
    // X is bitwise symmetric (0.5*(A+A^T)), so this matches max_sim - X[min][max]
    dist[idx] = (i == j) ? MAXD : __fsub_rn(max_sim, x);
    cross[idx] = (i == j) ? 0.0f : (W[idx] + W[j * D + i]);  // one addend is exactly 0
}

// ---------- kernel B2: initial per-row (min,argmin) over upper triangle ----------
__global__ void k_rowmin(const float* __restrict__ dist, float* __restrict__ values_g,
                         int* __restrict__ indices_g, const u32* __restrict__ scal) {
    int r = blockIdx.x;
    int lane = threadIdx.x;  // 64 threads = 1 wave
    float MAXD = __fmul_rn(dec_f(scal[1]), 1000.0f);
    u64 best = ((u64)__float_as_uint(MAXD) << 32);  // (MAXD, idx 0) like jnp.argmin on all-MAXD row
    const float* row = dist + (size_t)r * D;
    for (int j = lane; j < D; j += 64) {
        if (j > r) {
            u64 k = ((u64)__float_as_uint(row[j]) << 32) | (u32)j;
            if (k < best) best = k;
        }
    }
    for (int o = 32; o; o >>= 1) {
        u64 k2 = __shfl_xor(best, o);
        if (k2 < best) best = k2;
    }
    if (lane == 0) {
        values_g[r] = __uint_as_float((u32)(best >> 32));
        indices_g[r] = (int)(best & 0xffffffffu);
    }
}

// ---------- kernel C: persistent HAC loop, 256 threads (4 waves), 4 rows/thread ----
// values/indices are register-resident per owner thread; LDS vmail/imail is a
// mailbox (wave1 & rescan waves -> owner). Dying columns get MAXD stored to
// global dist, so rescans need no dead-mask. Global argmin via LDS u64
// atomicMin, key = valbits<<32 | row<<10 | argmin_col.
__global__ void __launch_bounds__(256) k_hac(
        float* __restrict__ dist, float* __restrict__ cross,
        const float* __restrict__ values_g, const int* __restrict__ indices_g,
        int* __restrict__ labels_g, const u32* __restrict__ scal) {
    __shared__ float vmail[D];
    __shared__ int imail[D];
    __shared__ __align__(16) float newv_l[D];
    __shared__ float cs_l[D];
    __shared__ int slot_l[D];   // leaf -> active slot id
    __shared__ int label_l[D];
    __shared__ double within_l[D];
    __shared__ double energy_l[D];
    __shared__ int rlist[2][D];
    __shared__ int nrec[2];
    __shared__ u64 s_best[2];   // double-buffered global-argmin accumulator
    __shared__ float s_cross12;
    __shared__ int s_takeP, s_m1P, s_labP;  // deferred cut (applied next iter)

    const int t = threadIdx.x;
    const int lane = t & 63, wid = t >> 6;
    const int r0 = 4 * t;  // first owned row/col
    const float MAXD = __fmul_rn(dec_f(scal[1]), 1000.0f);
    const u32 MAXDb = __float_as_uint(MAXD);

    float v[4];   // row-min values (canonical, register)
    int ix[4];    // row argmin cols (canonical, register)
    u32 aliveM = 0xFu;                      // liveness of 4 owned rows/cols
    bool resc[4] = {false, false, false, false};  // mailbox-reload flags

#pragma unroll
    for (int e = 0; e < 4; ++e) {
        int r = r0 + e;
        v[e] = values_g[r];
        ix[e] = indices_g[r];
        cs_l[r] = 1.0f;
        slot_l[r] = r;
        label_l[r] = r;
        within_l[r] = 0.0;
        energy_l[r] = 0.0;
    }
    if (t == 0) {
        s_takeP = 0; s_m1P = -1; s_labP = 0;
        nrec[0] = 0; nrec[1] = 0;
        s_best[0] = ~0ull; s_best[1] = ~0ull;
    }
    __syncthreads();
    // boot publish
    {
        u64 key = ~0ull;
#pragma unroll
        for (int e = 0; e < 4; ++e) {
            u64 k = ((u64)__float_as_uint(v[e]) << 32) | ((u32)(r0 + e) << 10) | (u32)ix[e];
            if (k < key) key = k;
        }
        for (int o = 32; o; o >>= 1) {
            u64 k2 = __shfl_xor(key, o);
            if (k2 < key) key = k2;
        }
        if (lane == 0) atomicMin(&s_best[0], key);
    }
    __syncthreads();

    for (int it = 0; it < D - 1; ++it) {
        const int cb = it & 1, pb = cb ^ 1;

        // ================= P2 =================
        const u64 bk = s_best[cb];  // one LDS read -> m1 AND m2
        const int m1 = (int)((bk >> 10) & 1023);
        const int m2 = (int)(bk & 1023);
        const float cs1 = cs_l[m1], cs2 = cs_l[m2];
        const float ncs = __fadd_rn(cs1, cs2);
        const int pm1 = s_m1P, ptake = s_takeP, plab = s_labP;

        // mailbox reload (rows rescanned / merged last iter), THEN freeze m2
#pragma unroll
        for (int e = 0; e < 4; ++e) {
            int r = r0 + e;
            if (resc[e] || r == pm1) { v[e] = vmail[r]; ix[e] = imail[r]; resc[e] = false; }
        }
        const bool ownM2 = ((m2 >> 2) == t);
        if (ownM2) {
            int e2 = m2 & 3;
            aliveM &= ~(1u << e2);
            v[e2] = MAXD;   // vmask freeze
            ix[e2] = 0;     // argmin of all-MAXD row
        }

        // global row loads, float4 (skippable if all 4 owned cols dead)
        const bool doLoad = (aliveM != 0u) || ownM2;
        float4 d1, d2, c1, c2;
        if (doLoad) {
            d1 = *(const float4*)(dist + (size_t)m1 * D + r0);
            d2 = *(const float4*)(dist + (size_t)m2 * D + r0);
            c1 = *(const float4*)(cross + (size_t)m1 * D + r0);
            c2 = *(const float4*)(cross + (size_t)m2 * D + r0);
        }

        // deferred label apply + slot merge (4 leaves)
#pragma unroll
        for (int e = 0; e < 4; ++e) {
            int l = r0 + e;
            int sl = slot_l[l];
            if (ptake && sl == pm1) label_l[l] = plab;
            if (sl == m2) slot_l[l] = m1;
        }

        float da[4] = {d1.x, d1.y, d1.z, d1.w};
        float db[4] = {d2.x, d2.y, d2.z, d2.w};
        float ea[4] = {c1.x, c1.y, c1.z, c1.w};
        float eb[4] = {c2.x, c2.y, c2.z, c2.w};
        if (ownM2) s_cross12 = ea[m2 & 3];  // old cross(m1,m2), read post-B2

        float nv[4], nc[4];
#pragma unroll
        for (int e = 0; e < 4; ++e) {
            int j = r0 + e;
            bool aj = (aliveM >> e) & 1u;
            nv[e] = (aj && j != m1)
                        ? __fdiv_rn(__fadd_rn(__fmul_rn(da[e], cs1), __fmul_rn(db[e], cs2)), ncs)
                        : MAXD;
            nc[e] = ea[e] + eb[e];  // garbage at dead cols: never read
        }
        *(float4*)&newv_l[r0] = make_float4(nv[0], nv[1], nv[2], nv[3]);
        if (aliveM) {
            *(float4*)(dist + (size_t)m1 * D + r0) = make_float4(nv[0], nv[1], nv[2], nv[3]);
            *(float4*)(cross + (size_t)m1 * D + r0) = make_float4(nc[0], nc[1], nc[2], nc[3]);
        }

        // incremental row-min maintenance (4 owned rows, registers)
        bool doR[4] = {false, false, false, false};
#pragma unroll
        for (int e = 0; e < 4; ++e) {
            int r = r0 + e;
            if (r == m1) continue;  // wave1 rebuilds row m1; reload via pm1 next iter
            if (((aliveM >> e) & 1u) && v[e] < MAXD) {
                if (ix[e] == m2) {
                    doR[e] = true;              // argmin retired -> rescan
                } else if (ix[e] == m1) {       // implies r < m1
                    if (nv[e] <= v[e]) v[e] = nv[e];  // lowest-col tie preserved
                    else doR[e] = true;
                } else if (r < m1) {            // col m1 got nv[e] in row r
                    if (nv[e] < v[e]) { v[e] = nv[e]; ix[e] = m1; }
                    else if (nv[e] == v[e] && m1 < ix[e]) ix[e] = m1;  // jnp tie-break
                }
            }
            if (doR[e]) {
                rlist[cb][atomicAdd(&nrec[cb], 1)] = r;
                resc[e] = true;
            }
        }

        // publish min over stable owned rows (rescan rows publish from P3)
        {
            u64 key = ~0ull;
#pragma unroll
            for (int e = 0; e < 4; ++e) {
                int r = r0 + e;
                if (r == m1 || doR[e]) continue;
                u64 k = ((u64)__float_as_uint(v[e]) << 32) | ((u32)r << 10) | (u32)ix[e];
                if (k < key) key = k;
            }
            for (int o = 32; o; o >>= 1) {
                u64 k2 = __shfl_xor(key, o);
                if (k2 < key) key = k2;
            }
            if (lane == 0) atomicMin(&s_best[pb], key);
        }
        __syncthreads();  // B2

        // ================= P3 =================
        // scattered col stores (drain overlaps scans): col m1 update, col m2 retire
        if (aliveM) {
#pragma unroll
            for (int e = 0; e < 4; ++e) {
                int j = r0 + e;
                if ((aliveM >> e) & 1u) {
                    dist[(size_t)j * D + m1] = nv[e];
                    cross[(size_t)j * D + m1] = nc[e];
                    dist[(size_t)j * D + m2] = MAXD;
                }
            }
        }
        if (ownM2) dist[(size_t)m1 * D + m2] = MAXD;  // row m1's retired col
        if ((m1 >> 2) == t) cs_l[m1] = ncs;
        if (t == 0) {
            s_best[cb] = ~0ull;  // consumed this iter; reset for iter it+2
            nrec[pb] = 0;
            // cut decision (f64 accumulators)
            double merge_e = within_l[m1] + within_l[m2] + (double)s_cross12;
            double e_sum = energy_l[m1] + energy_l[m2];
            int take = (merge_e >= e_sum) ? 1 : 0;
            within_l[m1] = merge_e;
            energy_l[m1] = take ? merge_e : e_sum;
            s_takeP = take;
            s_m1P = m1;
            s_labP = D + it;
        }
        if (wid == 1) {
            // row m1's new min from LDS newv_l (dead cols are MAXD by construction)
            u64 bb = ((u64)MAXDb << 32);  // (MAXD, col 0)
            const float4* nv4 = (const float4*)newv_l;
#pragma unroll
            for (int c = 0; c < 4; ++c) {
                float4 q = nv4[lane + 64 * c];
                int j0 = 4 * (lane + 64 * c);
                float qa[4] = {q.x, q.y, q.z, q.w};
#pragma unroll
                for (int e = 0; e < 4; ++e) {
                    int j = j0 + e;
                    if (j > m1) {
                        u64 k = ((u64)__float_as_uint(qa[e]) << 32) | (u32)j;
                        if (k < bb) bb = k;
                    }
                }
            }
            for (int o = 32; o; o >>= 1) {
                u64 k2 = __shfl_xor(bb, o);
                if (k2 < bb) bb = k2;
            }
            if (lane == 0) {
                vmail[m1] = __uint_as_float((u32)(bb >> 32));
                imail[m1] = (int)(bb & 0xffffffffu);
                atomicMin(&s_best[pb],
                          (bb & 0xffffffff00000000ull) | ((u32)m1 << 10) | (bb & 1023));
            }
        }
        // rescans: all 4 waves round-robin (dead cols hold MAXD in global)
        {
            const int n = nrec[cb];
            for (int q = wid; q < n; q += 4) {
                const int r = rlist[cb][q];
                const float subst = newv_l[r];  // col-m1 value (store in flight)
                u64 bb = ((u64)MAXDb << 32);    // (MAXD, col 0)
                const float4* row4 = (const float4*)(dist + (size_t)r * D);
#pragma unroll
                for (int c = 0; c < 4; ++c) {
                    float4 q4 = row4[lane + 64 * c];
                    int j0 = 4 * (lane + 64 * c);
                    float qa[4] = {q4.x, q4.y, q4.z, q4.w};
#pragma unroll
                    for (int e = 0; e < 4; ++e) {
                        int j = j0 + e;
                        float dv = (j == m1) ? subst : qa[e];
                        if (j > r && j != m2) {  // col m2's MAXD store may not be visible yet
                            u64 k = ((u64)__float_as_uint(dv) << 32) | (u32)j;
                            if (k < bb) bb = k;
                        }
                    }
                }
                for (int o = 32; o; o >>= 1) {
                    u64 k2 = __shfl_xor(bb, o);
                    if (k2 < bb) bb = k2;
                }
                if (lane == 0) {
                    vmail[r] = __uint_as_float((u32)(bb >> 32));
                    imail[r] = (int)(bb & 0xffffffffu);
                    atomicMin(&s_best[pb],
                              (bb & 0xffffffff00000000ull) | ((u32)r << 10) | (bb & 1023));
                }
            }
        }
        __syncthreads();  // B3
    }

    // apply the final iteration's deferred cut, then emit labels
#pragma unroll
    for (int e = 0; e < 4; ++e) {
        int l = r0 + e;
        int lab = label_l[l];
        if (s_takeP && slot_l[l] == s_m1P) lab = s_labP;
        labels_g[l] = lab;
    }
}

// ---------- kernel D: R[a][b] = (a==b) || (label[a]==label[b]) ----------
__global__ void k_out(const int* __restrict__ labels, float* __restrict__ out) {
    int idx = blockIdx.x * blockDim.x + threadIdx.x;
    if (idx >= D * D) return;
    int i = idx >> 10, j = idx & (D - 1);
    out[idx] = (i == j || labels[i] == labels[j]) ? 1.0f : 0.0f;
}

extern "C" void kernel_launch(void* const* d_in, const int* in_sizes, int n_in,
                              void* d_out, int out_size, void* d_ws, size_t ws_size,
                              hipStream_t stream) {
    const float* X = (const float*)d_in[0];
    const float* W = (const float*)d_in[1];

    char* ws = (char*)d_ws;
    const size_t MAT_BYTES = (size_t)D * D * sizeof(float);  // 4 MiB each
    float* dist = (float*)ws;
    float* cross = (float*)(ws + MAT_BYTES);
    float* values_g = (float*)(ws + 2 * MAT_BYTES);
    int* indices_g = (int*)(ws + 2 * MAT_BYTES + 4096);
    int* labels_g = (int*)(ws + 2 * MAT_BYTES + 8192);
    u32* scal = (u32*)(ws + 2 * MAT_BYTES + 12288);

    hipMemsetAsync(scal, 0, 2 * sizeof(u32), stream);
    k_maxred<<<256, 256, 0, stream>>>(X, scal);
    k_init<<<(D * D) / 256, 256, 0, stream>>>(X, W, dist, cross, scal);
    k_rowmin<<<D, 64, 0, stream>>>(dist, values_g, indices_g, scal);
    k_hac<<<1, 256, 0, stream>>>(dist, cross, values_g, indices_g, labels_g, scal);
    k_out<<<(D * D) / 256, 256, 0, stream>>>(labels_g, (float*)d_out);
}

// Round 10
// 3711.378 us; speedup vs baseline: 1.4512x; 1.4512x over previous
//
#include <hip/hip_runtime.h>
#include <stdint.h>

#define D 1024

typedef unsigned long long u64;
typedef unsigned int u32;

// ---------- monotonic float<->uint mapping for atomic max ----------
__device__ __forceinline__ u32 enc_f(float f) {
    u32 b = __float_as_uint(f);
    return (b & 0x80000000u) ? ~b : (b | 0x80000000u);
}
__device__ __forceinline__ float dec_f(u32 u) {
    u32 b = (u & 0x80000000u) ? (u ^ 0x80000000u) : ~u;
    return __uint_as_float(b);
}

// ---------- kernel A: max(X), max|X| ----------
__global__ void k_maxred(const float* __restrict__ X, u32* scal) {
    float mx = -INFINITY, ma = 0.f;
    int stride = gridDim.x * blockDim.x;
    for (int i = blockIdx.x * blockDim.x + threadIdx.x; i < D * D; i += stride) {
        float v = X[i];
        mx = fmaxf(mx, v);
        ma = fmaxf(ma, fabsf(v));
    }
    for (int o = 32; o; o >>= 1) {
        mx = fmaxf(mx, __shfl_xor(mx, o));
        ma = fmaxf(ma, __shfl_xor(ma, o));
    }
    if ((threadIdx.x & 63) == 0) {
        atomicMax(&scal[0], enc_f(mx));  // max_sim
        atomicMax(&scal[1], enc_f(ma));  // max|X|
    }
}

// ---------- kernel B: init dist (f32) and cross (f32) matrices ----------
__global__ void k_init(const float* __restrict__ X, const float* __restrict__ W,
                       float* __restrict__ dist, float* __restrict__ cross,
                       const u32* __restrict__ scal) {
    int idx = blockIdx.x * blockDim.x + threadIdx.x;
    if (idx >= D * D) return;
    float max_sim = dec_f(scal[0]);
    float MAXD = __fmul_rn(dec_f(scal[1]), 1000.0f);
    int i = idx >> 10, j = idx & (D - 1);
    float x = X[idx];
    // X is bitwise symmetric (0.5*(A+A^T)), so this matches max_sim - X[min][max]
    dist[idx] = (i == j) ? MAXD : __fsub_rn(max_sim, x);
    cross[idx] = (i == j) ? 0.0f : (W[idx] + W[j * D + i]);  // one addend is exactly 0
}

// ---------- kernel B2: initial per-row (min,argmin) over upper triangle ----------
__global__ void k_rowmin(const float* __restrict__ dist, float* __restrict__ values_g,
                         int* __restrict__ indices_g, const u32* __restrict__ scal) {
    int r = blockIdx.x;
    int lane = threadIdx.x;  // 64 threads = 1 wave
    float MAXD = __fmul_rn(dec_f(scal[1]), 1000.0f);
    u64 best = ((u64)__float_as_uint(MAXD) << 32);  // (MAXD, idx 0) like jnp.argmin on all-MAXD row
    const float* row = dist + (size_t)r * D;
    for (int j = lane; j < D; j += 64) {
        if (j > r) {
            u64 k = ((u64)__float_as_uint(row[j]) << 32) | (u32)j;
            if (k < best) best = k;
        }
    }
    for (int o = 32; o; o >>= 1) {
        u64 k2 = __shfl_xor(best, o);
        if (k2 < best) best = k2;
    }
    if (lane == 0) {
        values_g[r] = __uint_as_float((u32)(best >> 32));
        indices_g[r] = (int)(best & 0xffffffffu);
    }
}

// ---------- kernel C: persistent single-block HAC loop, 2 barriers/iter ----------
// P2 touches ONLY dist (2 loads); all cross work (row merge + cut decision via
// direct scalar load of cross[m1,m2] by wave2-lane0) lives in P3 where its
// latency overlaps the scan/rescan legs. Global argmin via LDS u64 atomicMin,
// key = valbits<<32 | row<<10 | argmin_col.
__global__ void __launch_bounds__(1024) k_hac(
        float* __restrict__ dist, float* __restrict__ cross,
        const float* __restrict__ values_g, const int* __restrict__ indices_g,
        int* __restrict__ labels_g, const u32* __restrict__ scal) {
    __shared__ __align__(16) float values_l[D];
    __shared__ float values_stage[D];   // P3 scan results (restored next P2)
    __shared__ int indices_l[D];
    __shared__ __align__(16) float newv_l[D];
    __shared__ float cs_l[D];
    __shared__ unsigned char dead_l[D];
    __shared__ unsigned char marked_l[D];  // row staged in P3 -> restore next P2
    __shared__ int slot_l[D];   // leaf -> active slot id
    __shared__ int label_l[D];
    __shared__ double within_l[D];   // touched only by wave2-lane0 after boot
    __shared__ double energy_l[D];   // touched only by wave2-lane0 after boot
    __shared__ int rlist[2][D];
    __shared__ int nrec[2];
    __shared__ u64 s_best[2];   // double-buffered global-argmin accumulator
    __shared__ int s_takeP, s_m1P, s_labP;  // deferred cut (applied next iter)

    const int t = threadIdx.x;
    const int lane = t & 63, wid = t >> 6;
    const float MAXD = __fmul_rn(dec_f(scal[1]), 1000.0f);
    const u32 MAXDb = __float_as_uint(MAXD);

    values_l[t] = values_g[t];
    indices_l[t] = indices_g[t];
    cs_l[t] = 1.0f;
    dead_l[t] = 0;
    marked_l[t] = 0;
    slot_l[t] = t;
    label_l[t] = t;
    within_l[t] = 0.0;
    energy_l[t] = 0.0;
    if (t == 0) {
        s_takeP = 0; s_m1P = -1; s_labP = 0;
        nrec[0] = 0; nrec[1] = 0;
        s_best[0] = ~0ull; s_best[1] = ~0ull;
    }
    __syncthreads();
    // boot publish: per-wave reduce over own 64 rows -> atomicMin into s_best[0]
    {
        u64 key = ((u64)__float_as_uint(values_l[t]) << 32) | ((u32)t << 10) |
                  (u32)indices_l[t];
        for (int o = 32; o; o >>= 1) {
            u64 k2 = __shfl_xor(key, o);
            if (k2 < key) key = k2;
        }
        if (lane == 0) atomicMin(&s_best[0], key);
    }
    __syncthreads();

    for (int it = 0; it < D - 1; ++it) {
        const int cb = it & 1, pb = cb ^ 1;

        // ================= P2 (dist only) =================
        const u64 bk = s_best[cb];  // one LDS read -> m1 AND m2
        const int m1 = (int)((bk >> 10) & 1023);
        const int m2 = (int)(bk & 1023);
        const float cs1 = cs_l[m1], cs2 = cs_l[m2];
        const float ncs = __fadd_rn(cs1, cs2);
        const int pm1 = s_m1P;
        if (t == 0) s_best[pb] = ~0ull;  // reset buffer this iter's publishers use

        // restore staged P3 results, then freeze m2 (own-thread writes only)
        if (marked_l[t]) { values_l[t] = values_stage[t]; marked_l[t] = 0; }
        if (t == m2) {
            dead_l[m2] = 1;
            values_l[m2] = MAXD;  // vmask freeze
            indices_l[m2] = 0;    // argmin of all-MAXD row
        }
        const bool alive = !dead_l[t];

        // the only global loads before B2
        float d1, d2;
        if (alive) {
            d1 = dist[(size_t)m1 * D + t];
            d2 = dist[(size_t)m2 * D + t];
        }

        // deferred label apply (prev iter's cut), then slot merge
        {
            int sl = slot_l[t];
            if (s_takeP && sl == pm1) label_l[t] = s_labP;
            if (sl == m2) slot_l[t] = m1;
        }

        float nv = MAXD;
        bool do_st = false;
        {
            if (alive && t != m1) {
                nv = __fdiv_rn(__fadd_rn(__fmul_rn(d1, cs1), __fmul_rn(d2, cs2)), ncs);
                dist[(size_t)m1 * D + t] = nv;  // row m1 (coalesced)
                do_st = true;                   // col store + cross work in P3
            }
            newv_l[t] = nv;  // MAXD-fill: wave1 scan needs no dead mask
        }
        // incremental row-min maintenance (thread t == row t)
        {
            float v = values_l[t];
            if (t == m1) {
                values_l[t] = MAXD;  // transient; wave1 stages the new min
                marked_l[t] = 1;
            } else if (alive && v < MAXD) {
                int idx = indices_l[t];
                if (idx == m2) {
                    rlist[cb][atomicAdd(&nrec[cb], 1)] = t;
                    values_l[t] = MAXD;
                    marked_l[t] = 1;
                } else if (idx == m1) {  // implies t < m1
                    if (nv <= v) values_l[t] = nv;  // lowest-index tie preserved
                    else {
                        rlist[cb][atomicAdd(&nrec[cb], 1)] = t;
                        values_l[t] = MAXD;
                        marked_l[t] = 1;
                    }
                } else if (t < m1) {  // col m1 got nv in row t
                    if (nv < v) { values_l[t] = nv; indices_l[t] = m1; }
                    else if (nv == v && m1 < idx) indices_l[t] = m1;  // jnp.argmin tie-break
                }
            }
        }
        __syncthreads();  // B2

        // ================= P3 =================
        // issue long-latency ops first so everything overlaps:
        // dist col store, cross row loads (consumed at the end of P3)
        float cc1, cc2;
        if (do_st) {
            dist[(size_t)t * D + m1] = nv;     // scattered col store
            cc1 = cross[(size_t)m1 * D + t];   // cross merge inputs
            cc2 = cross[(size_t)m2 * D + t];
        }
        if (t == m1) cs_l[m1] = ncs;  // nobody reads cs_l[m1] in P3
        const int n = nrec[cb];
        if (t == 0) nrec[pb] = 0;

        if (wid == 0) {
            // full argmin scan of values_l (marked rows are MAXD and stable;
            // their true keys come from wave1/rescan publishers)
            const float4* v4 = (const float4*)values_l;
            u64 bb = ~0ull;  // (val<<32)|row during reduce
#pragma unroll
            for (int c = 0; c < 4; ++c) {
                int fi = lane + 64 * c;
                float4 q = v4[fi];
                int b = fi << 2;
                u64 k;
                k = ((u64)__float_as_uint(q.x) << 32) | (u32)(b + 0); if (k < bb) bb = k;
                k = ((u64)__float_as_uint(q.y) << 32) | (u32)(b + 1); if (k < bb) bb = k;
                k = ((u64)__float_as_uint(q.z) << 32) | (u32)(b + 2); if (k < bb) bb = k;
                k = ((u64)__float_as_uint(q.w) << 32) | (u32)(b + 3); if (k < bb) bb = k;
            }
            for (int o = 32; o; o >>= 1) {
                u64 k2 = __shfl_xor(bb, o);
                if (k2 < bb) bb = k2;
            }
            if (lane == 0) {
                int r = (int)(bb & 1023);
                int idx = indices_l[r];  // r is unmarked -> stable during P3
                atomicMin(&s_best[pb],
                          (bb & 0xffffffff00000000ull) | ((u32)r << 10) | (u32)idx);
            }
        } else if (wid == 1) {
            // row m1's new min from LDS newv_l (dead cols are MAXD by construction)
            u64 bb = ((u64)MAXDb << 32);  // (val<<32)|col
            const float4* nv4 = (const float4*)newv_l;
            for (int c = lane; c < D / 4; c += 64) {
                float4 q = nv4[c];
                int j0 = c << 2;
#pragma unroll
                for (int e = 0; e < 4; ++e) {
                    int j = j0 + e;
                    float dv = (e == 0) ? q.x : (e == 1) ? q.y : (e == 2) ? q.z : q.w;
                    if (j > m1) {
                        u64 k = ((u64)__float_as_uint(dv) << 32) | (u32)j;
                        if (k < bb) bb = k;
                    }
                }
            }
            for (int o = 32; o; o >>= 1) {
                u64 k2 = __shfl_xor(bb, o);
                if (k2 < bb) bb = k2;
            }
            if (lane == 0) {
                values_stage[m1] = __uint_as_float((u32)(bb >> 32));
                indices_l[m1] = (int)(bb & 0xffffffffu);
                atomicMin(&s_best[pb],
                          (bb & 0xffffffff00000000ull) | ((u32)m1 << 10) | (bb & 1023));
            }
        } else if (wid == 2) {
            // cut decision: direct scalar load of cross(m1,m2) -- race-free,
            // since col m2 is dead and never stored this iteration.
            if (lane == 0) {
                float cr12 = cross[(size_t)m1 * D + m2];
                double merge_e = within_l[m1] + within_l[m2] + (double)cr12;
                double e_sum = energy_l[m1] + energy_l[m2];
                int take = (merge_e >= e_sum) ? 1 : 0;
                within_l[m1] = merge_e;
                energy_l[m1] = take ? merge_e : e_sum;
                s_takeP = take;
                s_m1P = m1;
                s_labP = D + it;
            }
        } else {
            // residual rescans (argmin retired/rose), one wave per row
            for (int q = wid - 3; q < n; q += 13) {
                const int r = rlist[cb][q];
                const float subst = newv_l[r];  // col-m1 value (store in flight)
                u64 bb = ((u64)MAXDb << 32);    // (val<<32)|col
                const float4* row4 = (const float4*)(dist + (size_t)r * D);
                for (int c = lane; c < D / 4; c += 64) {
                    float4 q4 = row4[c];
                    int j0 = c << 2;
#pragma unroll
                    for (int e = 0; e < 4; ++e) {
                        int j = j0 + e;
                        float dv = (e == 0) ? q4.x : (e == 1) ? q4.y : (e == 2) ? q4.z : q4.w;
                        if (j == m1) dv = subst;
                        if (j > r && !dead_l[j]) {
                            u64 k = ((u64)__float_as_uint(dv) << 32) | (u32)j;
                            if (k < bb) bb = k;
                        }
                    }
                }
                for (int o = 32; o; o >>= 1) {
                    u64 k2 = __shfl_xor(bb, o);
                    if (k2 < bb) bb = k2;
                }
                if (lane == 0) {
                    values_stage[r] = __uint_as_float((u32)(bb >> 32));
                    indices_l[r] = (int)(bb & 0xffffffffu);
                    atomicMin(&s_best[pb],
                              (bb & 0xffffffff00000000ull) | ((u32)r << 10) | (bb & 1023));
                }
            }
        }

        // cross row merge + symmetric stores (loads issued at P3 top; their
        // latency is hidden behind the scan legs above)
        if (do_st) {
            float ncx = cc1 + cc2;
            cross[(size_t)m1 * D + t] = ncx;
            cross[(size_t)t * D + m1] = ncx;
        }
        __syncthreads();  // B3 (drains all stores; publishes mailbox + s_best)
    }

    // apply the final iteration's deferred cut, then emit labels
    {
        int lab = label_l[t];
        if (s_takeP && slot_l[t] == s_m1P) lab = s_labP;
        labels_g[t] = lab;
    }
}

// ---------- kernel D: R[a][b] = (a==b) || (label[a]==label[b]) ----------
__global__ void k_out(const int* __restrict__ labels, float* __restrict__ out) {
    int idx = blockIdx.x * blockDim.x + threadIdx.x;
    if (idx >= D * D) return;
    int i = idx >> 10, j = idx & (D - 1);
    out[idx] = (i == j || labels[i] == labels[j]) ? 1.0f : 0.0f;
}

extern "C" void kernel_launch(void* const* d_in, const int* in_sizes, int n_in,
                              void* d_out, int out_size, void* d_ws, size_t ws_size,
                              hipStream_t stream) {
    const float* X = (const float*)d_in[0];
    const float* W = (const float*)d_in[1];

    char* ws = (char*)d_ws;
    const size_t MAT_BYTES = (size_t)D * D * sizeof(float);  // 4 MiB each
    float* dist = (float*)ws;
    float* cross = (float*)(ws + MAT_BYTES);
    float* values_g = (float*)(ws + 2 * MAT_BYTES);
    int* indices_g = (int*)(ws + 2 * MAT_BYTES + 4096);
    int* labels_g = (int*)(ws + 2 * MAT_BYTES + 8192);
    u32* scal = (u32*)(ws + 2 * MAT_BYTES + 12288);

    hipMemsetAsync(scal, 0, 2 * sizeof(u32), stream);
    k_maxred<<<256, 256, 0, stream>>>(X, scal);
    k_init<<<(D * D) / 256, 256, 0, stream>>>(X, W, dist, cross, scal);
    k_rowmin<<<D, 64, 0, stream>>>(dist, values_g, indices_g, scal);
    k_hac<<<1, 1024, 0, stream>>>(dist, cross, values_g, indices_g, labels_g, scal);
    k_out<<<(D * D) / 256, 256, 0, stream>>>(labels_g, (float*)d_out);
}